// Round 1
// baseline (2901.468 us; speedup 1.0000x reference)
//
#include <hip/hip_runtime.h>
#include <hip/hip_fp16.h>

// Decoder: packed-sequence GRU (r,z,n gate order) + log_softmax output head.
// T=512, B=1024, V=64, H=100, all fp32 inputs, fp32 output [T,B,V].
//
// Kernel 1 (gru_seq): one block per batch row; t-loop inside the kernel.
//   Thread j<300 holds W_ih[j,:] (64 regs) + W_hh[j,:] (100 regs) in VGPRs.
//   x_t / h broadcast from LDS (float4 reads). Writes h_t as f16 into the
//   first 200B of the 256B output row (t,b) -- no workspace needed.
// Kernel 2 (out_head): lane v holds W_out[v,:] in 100 VGPRs; h broadcast via
//   v_readlane; 64-lane shfl_xor log-softmax; overwrites rows in place.

#define T_STEPS 512
#define BATCH   1024
#define VOCAB   64
#define HID     100

__device__ __forceinline__ float fast_sigmoid(float x) {
    return 1.0f / (1.0f + __expf(-x));
}
__device__ __forceinline__ float fast_tanh(float x) {
    // 1 - 2/(exp(2x)+1); saturates correctly at +/-1 for large |x|
    return 1.0f - 2.0f / (__expf(2.0f * x) + 1.0f);
}

__global__ __launch_bounds__(320, 2) void gru_seq(
    const float* __restrict__ x, const float* __restrict__ h0,
    const int* __restrict__ lengths,
    const float* __restrict__ W_ih, const float* __restrict__ W_hh,
    const float* __restrict__ b_ih, const float* __restrict__ b_hh,
    float* __restrict__ out)
{
    const int tid = threadIdx.x;
    const int b   = blockIdx.x;

    __shared__ alignas(16) float xs[VOCAB];
    __shared__ alignas(16) float hs[HID];
    __shared__ float gr[HID], gz[HID], gin[HID], ghn[HID];

    // Per-thread weight rows in registers (threads 0..299).
    float wih[VOCAB];
    float whh[HID];
    float bi = 0.f, bh = 0.f;
    if (tid < 3 * HID) {
        const float4* wi4 = reinterpret_cast<const float4*>(W_ih + (size_t)tid * VOCAB);
#pragma unroll
        for (int q = 0; q < VOCAB / 4; ++q) {
            float4 v = wi4[q];
            wih[4*q+0] = v.x; wih[4*q+1] = v.y; wih[4*q+2] = v.z; wih[4*q+3] = v.w;
        }
        const float4* wh4 = reinterpret_cast<const float4*>(W_hh + (size_t)tid * HID);
#pragma unroll
        for (int q = 0; q < HID / 4; ++q) {
            float4 v = wh4[q];
            whh[4*q+0] = v.x; whh[4*q+1] = v.y; whh[4*q+2] = v.z; whh[4*q+3] = v.w;
        }
        bi = b_ih[tid];
        bh = b_hh[tid];
    }
    if (tid < HID) hs[tid] = h0[(size_t)b * HID + tid];
    const int len = lengths[b];

    const float* xrow = x + (size_t)b * VOCAB;
    float xreg = 0.f;
    if (tid < VOCAB) xreg = xrow[tid];  // x at t=0

    __half* hout_base = reinterpret_cast<__half*>(out);

    for (int t = 0; t < T_STEPS; ++t) {
        // Stage x_t (prefetched last iter) into LDS.
        if (tid < VOCAB) xs[tid] = xreg;
        __syncthreads();  // xs ready; hs holds h_{t-1}

        // Prefetch x_{t+1}: latency hidden under compute phase.
        if (tid < VOCAB) {
            const int tn = (t + 1 < T_STEPS) ? (t + 1) : t;
            xreg = xrow[(size_t)tn * (BATCH * VOCAB) + tid];
        }

        if (tid < 3 * HID) {
            float a = bi;   // input projection  gi[j]
            float g = bh;   // hidden projection gh[j]
#pragma unroll
            for (int v = 0; v < VOCAB; v += 4) {
                float4 xv = *reinterpret_cast<const float4*>(&xs[v]);
                a = fmaf(xv.x, wih[v+0], a);
                a = fmaf(xv.y, wih[v+1], a);
                a = fmaf(xv.z, wih[v+2], a);
                a = fmaf(xv.w, wih[v+3], a);
            }
#pragma unroll
            for (int k = 0; k < HID; k += 4) {
                float4 hv = *reinterpret_cast<const float4*>(&hs[k]);
                g = fmaf(hv.x, whh[k+0], g);
                g = fmaf(hv.y, whh[k+1], g);
                g = fmaf(hv.z, whh[k+2], g);
                g = fmaf(hv.w, whh[k+3], g);
            }
            if (tid < HID)            gr[tid]           = a + g;
            else if (tid < 2 * HID)   gz[tid - HID]     = a + g;
            else { gin[tid - 2*HID] = a; ghn[tid - 2*HID] = g; }
        }
        __syncthreads();  // gate pre-activations ready

        if (tid < HID) {
            float r    = fast_sigmoid(gr[tid]);
            float z    = fast_sigmoid(gz[tid]);
            float n    = fast_tanh(fmaf(r, ghn[tid], gin[tid]));
            float hold = hs[tid];
            float hnew = (1.f - z) * n + z * hold;
            float hv   = (t < len) ? hnew : hold;
            hs[tid] = hv;
            // Stash h_t as f16 in the output row (first 200B of 256B row).
            __half* hrow = hout_base + ((size_t)t * BATCH + b) * (VOCAB * 2);
            hrow[tid] = __float2half(hv);
        }
        // next iteration's first __syncthreads orders hs/xs writes vs reads
    }
}

__global__ __launch_bounds__(256, 2) void out_head(
    float* __restrict__ out, const float* __restrict__ W_out,
    const float* __restrict__ b_out, const int* __restrict__ lengths,
    int nwaves)
{
    const int lane = threadIdx.x & 63;
    const int wid  = blockIdx.x * (blockDim.x >> 6) + (threadIdx.x >> 6);

    // Lane v holds W_out[v,:] (100 regs).
    float w[HID];
    const float4* wr = reinterpret_cast<const float4*>(W_out + (size_t)lane * HID);
#pragma unroll
    for (int q = 0; q < HID / 4; ++q) {
        float4 v = wr[q];
        w[4*q+0] = v.x; w[4*q+1] = v.y; w[4*q+2] = v.z; w[4*q+3] = v.w;
    }
    const float bo = b_out[lane];

    const int total = T_STEPS * BATCH;
    for (int r = wid; r < total; r += nwaves) {
        const int t  = r >> 10;
        const int bb = r & (BATCH - 1);
        float* row = out + (size_t)r * VOCAB;
        if (t >= lengths[bb]) { row[lane] = 0.f; continue; }

        // Read h_t (f16 pairs) through float loads (no type-aliasing hazard
        // with the float store below), then broadcast via v_readlane.
        float fx = 0.f, fy = 0.f;
        if (lane < HID / 2) {
            unsigned int hb = __float_as_uint(row[lane]);
            __half2 hh = *reinterpret_cast<__half2*>(&hb);
            float2 hf = __half22float2(hh);
            fx = hf.x; fy = hf.y;
        }
        float acc = bo;
#pragma unroll
        for (int i = 0; i < HID / 2; ++i) {
            float ax = __uint_as_float((unsigned)__builtin_amdgcn_readlane((int)__float_as_uint(fx), i));
            float ay = __uint_as_float((unsigned)__builtin_amdgcn_readlane((int)__float_as_uint(fy), i));
            acc = fmaf(ax, w[2*i+0], acc);
            acc = fmaf(ay, w[2*i+1], acc);
        }
        // 64-lane log_softmax
        float m = acc;
#pragma unroll
        for (int off = 32; off >= 1; off >>= 1) m = fmaxf(m, __shfl_xor(m, off));
        float e = __expf(acc - m);
        float s = e;
#pragma unroll
        for (int off = 32; off >= 1; off >>= 1) s += __shfl_xor(s, off);
        row[lane] = (acc - m) - __logf(s);
    }
}

extern "C" void kernel_launch(void* const* d_in, const int* in_sizes, int n_in,
                              void* d_out, int out_size, void* d_ws, size_t ws_size,
                              hipStream_t stream) {
    const float* x      = (const float*)d_in[0];
    const float* h0     = (const float*)d_in[1];
    const int*   lens   = (const int*)  d_in[2];
    const float* W_ih   = (const float*)d_in[3];
    const float* W_hh   = (const float*)d_in[4];
    const float* b_ih   = (const float*)d_in[5];
    const float* b_hh   = (const float*)d_in[6];
    const float* W_out  = (const float*)d_in[7];
    const float* b_out  = (const float*)d_in[8];
    float* out = (float*)d_out;

    gru_seq<<<BATCH, 320, 0, stream>>>(x, h0, lens, W_ih, W_hh, b_ih, b_hh, out);

    const int blocksB = 1024, thrB = 256;
    out_head<<<blocksB, thrB, 0, stream>>>(out, W_out, b_out, lens,
                                           blocksB * (thrB / 64));
}